// Round 3
// baseline (269.765 us; speedup 1.0000x reference)
//
#include <hip/hip_runtime.h>
#include <hip/hip_bf16.h>
#include <math.h>

// R10: k_mconv made fully wave-autonomous (zero barriers in the K-loop).
//   R9 post-mortem: 2268 cyc/K-step vs ~700 cyc of per-pipe demand -> 3x
//   serialization from the vmcnt->barrier->ds_read->lgkmcnt(0)->barrier chain
//   with only 2 waves per barrier domain.
//   - A fragments now load straight global->VGPR (16 full 64B lines per
//     global_load_dwordx4, L1-backed across the block's 2 waves), register
//     double-buffered: prefetch K+1 during K's MFMAs.
//   - B is wave-PRIVATE in LDS (each wave stages its own 64-row half,
//     4 global_load_lds/step, 2 buffers, 16 KB/block) -> no cross-wave
//     dependency -> no s_barrier at all. WAR safe by construction: a
//     buffer's re-stage lands >=1 iteration after its reads retired.
//   - one counted s_waitcnt vmcnt(10) per K-step (6 A + 4 B in flight),
//     sched_barrier(0) pin after it. vmcnt(0) only on the final step.
//   Same MFMA fragments & accumulation order as R9 -> bit-exact epilogue.
//   Other kernels unchanged.

typedef __attribute__((ext_vector_type(8))) short short8;
typedef __attribute__((ext_vector_type(4))) float f32x4;

#define T_ 4
#define B_ 4
#define C_ 384
#define HW 1024
#define NH_ 12
#define Np_ 256
#define EPS_ 1e-5f
#define LDK 56

static __device__ __forceinline__ unsigned short f2bf(float f) {
    __hip_bfloat16 h = __float2bfloat16(f);
    return *reinterpret_cast<unsigned short*>(&h);
}
static __device__ __forceinline__ float bf2f(unsigned short u) {
    __hip_bfloat16 h = *reinterpret_cast<__hip_bfloat16*>(&u);
    return __bfloat162float(h);
}
static __device__ __forceinline__ void split3(float w, unsigned short& u0,
                                              unsigned short& u1, unsigned short& u2) {
    u0 = f2bf(w);  float f0 = bf2f(u0);
    float r1 = w - f0;
    u1 = f2bf(r1); float f1 = bf2f(u1);
    u2 = f2bf(r1 - f1);
}

// ---------------- K0: weight 3-way bf16 split ----------------
__global__ __launch_bounds__(256) void k_wsplit(const float* __restrict__ Wc,
                                                const float* __restrict__ Wp,
                                                unsigned short* __restrict__ Wc3,
                                                unsigned short* __restrict__ Wp3) {
    const int NC = 768 * 1536;
    const int NP = 384 * 384;
    int i = blockIdx.x * 256 + threadIdx.x;
    float w; unsigned short* dst; int idx, plane;
    if (i < NC) { w = Wc[i]; dst = Wc3; idx = i; plane = NC; }
    else {
        int j = i - NC;
        if (j >= NP) return;
        w = Wp[j]; dst = Wp3; idx = j; plane = NP;
    }
    unsigned short u0, u1, u2;
    split3(w, u0, u1, u2);
    dst[idx] = u0; dst[plane + idx] = u1; dst[2 * plane + idx] = u2;
}

// ---------------- K1: LIF(x) fused with im2col -> Bc[n][k] bf16, + xsb[tb][c][hw] bf16 ----
__global__ __launch_bounds__(256) void k_lif_im2col(const float* __restrict__ x,
                                                    unsigned short* __restrict__ Bc,
                                                    unsigned short* __restrict__ xsb) {
    int gt = blockIdx.x * 256 + threadIdx.x;
    int pw = gt & 15, ph = (gt >> 4) & 15;
    int v = gt >> 8;
    int c = v % 384, b = v / 384;
    float v00 = 0.f, v01 = 0.f, v10 = 0.f, v11 = 0.f;
    const size_t xrow = ((size_t)b * C_ + c) * HW + (size_t)(2 * ph) * 32 + 2 * pw;
#pragma unroll
    for (int t = 0; t < T_; ++t) {
        const float* px = x + (size_t)t * (B_ * C_ * HW) + xrow;
        float2 r0 = *(const float2*)px;
        float2 r1 = *(const float2*)(px + 32);
        v00 += (r0.x - v00) * 0.5f;
        v01 += (r0.y - v01) * 0.5f;
        v10 += (r1.x - v10) * 0.5f;
        v11 += (r1.y - v11) * 0.5f;
        ushort4 s;
        s.x = (v00 >= 1.f) ? 0x3F80 : 0; if (v00 >= 1.f) v00 = 0.f;
        s.y = (v01 >= 1.f) ? 0x3F80 : 0; if (v01 >= 1.f) v01 = 0.f;
        s.z = (v10 >= 1.f) ? 0x3F80 : 0; if (v10 >= 1.f) v10 = 0.f;
        s.w = (v11 >= 1.f) ? 0x3F80 : 0; if (v11 >= 1.f) v11 = 0.f;
        int tb = t * B_ + b;
        int n = tb * 256 + ph * 16 + pw;
        *(ushort4*)(Bc + (size_t)n * 1536 + 4 * c) = s;
        size_t xo = ((size_t)tb * C_ + c) * HW + (size_t)(2 * ph) * 32 + 2 * pw;
        ushort2 w0 = {s.x, s.y}, w1 = {s.z, s.w};
        *(ushort2*)(xsb + xo) = w0;
        *(ushort2*)(xsb + xo + 32) = w1;
    }
}

// ---------------- K2: conv GEMM via MFMA; epilogue emits scaled 3-split y1s/y2s ----------
#define GL16(GP, LP) __builtin_amdgcn_global_load_lds(                        \
    (const __attribute__((address_space(1))) void*)(GP),                      \
    (__attribute__((address_space(3))) void*)(LP), 16, 0, 0)

// A fragments: direct global->VGPR, per-lane base aBase = row(mb*32+lr), col quad*8.
static __device__ __forceinline__ void ldA(short8 af[3][2],
                                           const unsigned short* aBase, int k0) {
#pragma unroll
    for (int s = 0; s < 3; ++s)
#pragma unroll
        for (int im = 0; im < 2; ++im)
            af[s][im] = *(const short8*)(aBase + (size_t)(s * 768 + im * 16) * 1536 + k0);
}

// B staging: wave-private 64 rows x 32 shorts, within-64B-line XOR chunk swizzle
// on the global source (LDS[row][c] holds chunk c ^ ((row>>1)&3)).
static __device__ __forceinline__ void stageB(const unsigned short* bSrc,
                                              short* bbuf, int k0) {
#pragma unroll
    for (int v = 0; v < 4; ++v)
        GL16(bSrc + (size_t)v * 16 * 1536 + k0, bbuf + v * 512);
}

static __device__ __forceinline__ void mfma_step(f32x4 acc[2][4], const short8 af[3][2],
                                                 const short* bbuf, int lr, int slot) {
    short8 bf[4];
#pragma unroll
    for (int in = 0; in < 4; ++in)
        bf[in] = *(const short8*)&bbuf[(in * 16 + lr) * 32 + slot * 8];
#pragma unroll
    for (int s = 0; s < 3; ++s)
#pragma unroll
        for (int im = 0; im < 2; ++im)
#pragma unroll
            for (int in = 0; in < 4; ++in)
                acc[im][in] = __builtin_amdgcn_mfma_f32_16x16x32_bf16(af[s][im], bf[in], acc[im][in], 0, 0, 0);
}

__global__ __launch_bounds__(128) void k_mconv(const unsigned short* __restrict__ Bc,
                                               const unsigned short* __restrict__ Wc3,
                                               const float* __restrict__ g1,
                                               const float* __restrict__ b1,
                                               const float* __restrict__ frx,
                                               const float* __restrict__ fra,
                                               unsigned short* __restrict__ y1s,
                                               unsigned short* __restrict__ y2s) {
    __shared__ short bs[2][2][2048];              // [wid][buf][64 rows x 32 shorts] = 16 KiB
    const int nb = blockIdx.x, mb = blockIdx.y;   // nb: 0..31 (N/128), mb: 0..23 (M/32)
    const int tid = threadIdx.x;
    const int lane = tid & 63, wid = tid >> 6;    // 2 autonomous waves; wn = wid
    const int quad = lane >> 4, lr = lane & 15;
    const int rloc = lane >> 2;                   // staging: 4 lanes per 64B row
    const int cswz = (lane & 3) ^ ((lane >> 3) & 3);   // source chunk swizzle
    const int slot = quad ^ ((lr >> 1) & 3);      // ds_read chunk swizzle
    const int wn = wid;

    const unsigned short* aBase = Wc3 + (size_t)(mb * 32 + lr) * 1536 + quad * 8;
    const unsigned short* bSrc  = Bc + (size_t)(nb * 128 + wn * 64 + rloc) * 1536 + cswz * 8;
    short* bb0 = &bs[wid][0][0];
    short* bb1 = &bs[wid][1][0];

    f32x4 acc[2][4];
#pragma unroll
    for (int im = 0; im < 2; ++im)
#pragma unroll
        for (int in = 0; in < 4; ++in)
            acc[im][in] = (f32x4){0.f, 0.f, 0.f, 0.f};

    short8 afA[3][2], afB[3][2];
    ldA(afA, aBase, 0);
    stageB(bSrc, bb0, 0);

    for (int kt = 0; kt < 48; kt += 2) {
        // even half: consume (afA, bb0, k=kt); prefetch kt+1 into (afB, bb1)
        {
            int kn = (kt + 1) * 32;
            ldA(afB, aBase, kn);                  // kt+1 < 48 always here
            stageB(bSrc, bb1, kn);
            asm volatile("s_waitcnt vmcnt(10)" ::: "memory");   // kt's 10 done
            __builtin_amdgcn_sched_barrier(0);
            mfma_step(acc, afA, bb0, lr, slot);
        }
        // odd half: consume (afB, bb1, k=kt+1); prefetch kt+2 into (afA, bb0)
        {
            int kn = (kt + 2) * 32;
            if (kn < 1536) {
                ldA(afA, aBase, kn);
                stageB(bSrc, bb0, kn);
                asm volatile("s_waitcnt vmcnt(10)" ::: "memory");
            } else {
                asm volatile("s_waitcnt vmcnt(0)" ::: "memory");
            }
            __builtin_amdgcn_sched_barrier(0);
            mfma_step(acc, afB, bb1, lr, slot);
        }
    }

    const float rs = 1.0f / sqrtf(1.0f + EPS_);
    const int h = mb >> 1, half = mb & 1;         // mb*32 = h*64 + half*32
    const float scl = (half == 0) ? (1.0f / sqrtf(frx[h] * 32.0f))
                                  : (1.0f / sqrtf(fra[h] * 256.0f));
    unsigned short* dst = (half == 0) ? y1s : y2s;
#pragma unroll
    for (int im = 0; im < 2; ++im) {
#pragma unroll
        for (int in = 0; in < 4; ++in) {
            int n_g = nb * 128 + wn * 64 + in * 16 + lr;
            int tb = n_g >> 8, pn = n_g & 255;
            size_t base = (size_t)(tb * NH_ + h) * 3 * 8192;
            ushort4 o0, o1, o2;
#pragma unroll
            for (int r = 0; r < 4; ++r) {
                int oc = mb * 32 + im * 16 + quad * 4 + r;
                float val = (acc[im][in][r] * (g1[oc] * rs) + b1[oc]) * scl;
                unsigned short u0, u1, u2;
                split3(val, u0, u1, u2);
                ((unsigned short*)&o0)[r] = u0;
                ((unsigned short*)&o1)[r] = u1;
                ((unsigned short*)&o2)[r] = u2;
            }
            int dd = im * 16 + quad * 4;
            if (half == 0) {
                *(ushort4*)&dst[base + 0 * 8192 + (size_t)pn * 32 + dd] = o0;
                *(ushort4*)&dst[base + 1 * 8192 + (size_t)pn * 32 + dd] = o1;
                *(ushort4*)&dst[base + 2 * 8192 + (size_t)pn * 32 + dd] = o2;
            } else {
#pragma unroll
                for (int r = 0; r < 4; ++r) {
                    dst[base + 0 * 8192 + (size_t)(dd + r) * 256 + pn] = ((unsigned short*)&o0)[r];
                    dst[base + 1 * 8192 + (size_t)(dd + r) * 256 + pn] = ((unsigned short*)&o1)[r];
                    dst[base + 2 * 8192 + (size_t)(dd + r) * 256 + pn] = ((unsigned short*)&o2)[r];
                }
            }
        }
    }
}

// ---------------- K3a: ein1 + attn-LIF -> packed spike bits ----------------
__global__ __launch_bounds__(256, 2) void k_attn_qk(const unsigned short* __restrict__ xsb,
                                                    const unsigned short* __restrict__ y1s,
                                                    unsigned short* __restrict__ abq) {
    __shared__ unsigned short xb[4][64][40];   // [t][m][d] : 20,480 B
    const int h = blockIdx.y, b = blockIdx.z;
    const int tid = threadIdx.x;
    const int lane = tid & 63, wq = tid >> 6;
    const int quad = lane >> 4, lr = lane & 15;
    const int m0 = blockIdx.x * 64;

#pragma unroll
    for (int i = 0; i < 8; ++i) {
        int e = tid + i * 256;                 // 2048 ushort4 = 4t*64m*32d
        int j4 = e & 15, d = (e >> 4) & 31, t = e >> 9;
        ushort4 v = *(const ushort4*)(xsb + ((size_t)((t * B_ + b) * C_) + h * 32 + d) * HW + m0 + j4 * 4);
        xb[t][j4 * 4 + 0][d] = v.x;
        xb[t][j4 * 4 + 1][d] = v.y;
        xb[t][j4 * 4 + 2][d] = v.z;
        xb[t][j4 * 4 + 3][d] = v.w;
    }
    __syncthreads();   // only barrier; t/m loops below are wave-autonomous

    float vat[4][4][4];   // [mi][itl][r] attn-LIF state
#pragma unroll
    for (int mi = 0; mi < 4; ++mi)
#pragma unroll
        for (int itl = 0; itl < 4; ++itl)
#pragma unroll
            for (int r = 0; r < 4; ++r) vat[mi][itl][r] = 0.f;

#pragma unroll
    for (int t = 0; t < T_; ++t) {
        const int tb = t * B_ + b;
        const size_t slab = (size_t)(tb * NH_ + h) * 3 * 8192;

        // m-invariant A-fragments: 12 loads, reused by all 4 m-tiles
        short8 af[3][4];
        const unsigned short* y1p = y1s + slab + (size_t)(wq * 64 + lr) * 32 + quad * 8;
#pragma unroll
        for (int s = 0; s < 3; ++s)
#pragma unroll
            for (int itl = 0; itl < 4; ++itl)
                af[s][itl] = *(const short8*)(y1p + s * 8192 + itl * 512);

#pragma unroll
        for (int mi = 0; mi < 4; ++mi) {
            short8 bx = *(const short8*)&xb[t][mi * 16 + lr][quad * 8];
            f32x4 acc[4];
#pragma unroll
            for (int itl = 0; itl < 4; ++itl) acc[itl] = (f32x4){0.f, 0.f, 0.f, 0.f};
#pragma unroll
            for (int s = 0; s < 3; ++s)
#pragma unroll
                for (int itl = 0; itl < 4; ++itl)
                    acc[itl] = __builtin_amdgcn_mfma_f32_16x16x32_bf16(af[s][itl], bx, acc[itl], 0, 0, 0);

            unsigned int q = 0;
#pragma unroll
            for (int itl = 0; itl < 4; ++itl)
#pragma unroll
                for (int r = 0; r < 4; ++r) {
                    float v = vat[mi][itl][r];
                    v += (acc[itl][r] - v) * 0.5f;
                    bool s = (v >= 1.0f);
                    vat[mi][itl][r] = s ? 0.f : v;
                    q |= (s ? 1u : 0u) << (itl * 4 + r);
                }
            int m = m0 + mi * 16 + lr;
            abq[(((size_t)(tb * NH_ + h) * 1024 + m) * 4 + quad) * 4 + wq] = (unsigned short)q;
        }
    }
}

// ---------------- K3b: ein2 + out-LIF (no LDS, no barriers) ----------------
__global__ __launch_bounds__(256, 1) void k_attn_pv(const unsigned long long* __restrict__ abits,
                                                    const unsigned short* __restrict__ y2s,
                                                    unsigned short* __restrict__ obt) {
    const int h = blockIdx.y, b = blockIdx.z;
    const int tid = threadIdx.x;
    const int lane = tid & 63, wv = tid >> 6;
    const int quad = lane >> 4, lr = lane & 15;
    const int dt = wv >> 1, mg = wv & 1;
    const int mbase = blockIdx.x * 128 + mg * 64;
    const int obase = (quad & 2) << 1;   // 0 or 4

    float vo[4][4];
#pragma unroll
    for (int mi = 0; mi < 4; ++mi)
#pragma unroll
        for (int r = 0; r < 4; ++r) vo[mi][r] = 0.f;

#pragma unroll
    for (int t = 0; t < T_; ++t) {
        const int tb = t * B_ + b;
        const size_t slab = (size_t)(tb * NH_ + h) * 3 * 8192;

        // m-invariant A-fragments: 24 loads, reused by all 4 m-tiles
        short8 ay[3][8];
        const unsigned short* y2p = y2s + slab + (size_t)(dt * 16 + lr) * 256 + quad * 8;
#pragma unroll
        for (int s = 0; s < 3; ++s)
#pragma unroll
            for (int kt = 0; kt < 8; ++kt)
                ay[s][kt] = *(const short8*)(y2p + s * 8192 + kt * 32);

#pragma unroll
        for (int mi = 0; mi < 4; ++mi) {
            const int m = mbase + mi * 16 + lr;
            const unsigned long long* ap = abits + ((size_t)(tb * NH_ + h) * 1024 + m) * 4 + (quad & 1) * 2;
            unsigned long long Qa = ap[0];
            unsigned long long Qb = ap[1];

            short8 bs[8];
#pragma unroll
            for (int kt = 0; kt < 8; ++kt) {
                int o = kt * 8 + obase;
                unsigned int a4 = (unsigned int)(Qa >> o) & 15u;
                unsigned int b4 = (unsigned int)(Qb >> o) & 15u;
                union { short8 v; unsigned int w[4]; } u;
                u.w[0] = ((a4 & 1u) ? 0x3F80u : 0u) | ((a4 & 2u) ? 0x3F800000u : 0u);
                u.w[1] = ((a4 & 4u) ? 0x3F80u : 0u) | ((a4 & 8u) ? 0x3F800000u : 0u);
                u.w[2] = ((b4 & 1u) ? 0x3F80u : 0u) | ((b4 & 2u) ? 0x3F800000u : 0u);
                u.w[3] = ((b4 & 4u) ? 0x3F80u : 0u) | ((b4 & 8u) ? 0x3F800000u : 0u);
                bs[kt] = u.v;
            }

            f32x4 acc2 = (f32x4){0.f, 0.f, 0.f, 0.f};
#pragma unroll
            for (int s = 0; s < 3; ++s)
#pragma unroll
                for (int kt = 0; kt < 8; ++kt)
                    acc2 = __builtin_amdgcn_mfma_f32_16x16x32_bf16(ay[s][kt], bs[kt], acc2, 0, 0, 0);

            ushort4 ob;
#pragma unroll
            for (int r = 0; r < 4; ++r) {
                float v = vo[mi][r];
                v += (acc2[r] - v) * 0.5f;
                bool s = (v >= 1.0f);
                ((unsigned short*)&ob)[r] = s ? 0x3F80 : 0;
                vo[mi][r] = s ? 0.f : v;
            }
            *(ushort4*)(obt + ((size_t)tb * HW + m) * C_ + h * 32 + dt * 16 + quad * 4) = ob;
        }
    }
}

// ---------------- K4: proj GEMM via MFMA + BN2 + residual ----------------
__global__ __launch_bounds__(256) void k_mproj(const unsigned short* __restrict__ obt,
                                               const unsigned short* __restrict__ Wp3,
                                               const float* __restrict__ g2,
                                               const float* __restrict__ b2,
                                               const float* __restrict__ x,
                                               float* __restrict__ out) {
    __shared__ short As[3][64][LDK];
    __shared__ short Bs[128][LDK];
    const int nb = blockIdx.x, mb = blockIdx.y;
    const int tid = threadIdx.x;
    const int lane = tid & 63, wave = tid >> 6;
    const int wm = wave >> 1, wn = wave & 1;
    const int quad = lane >> 4, lr = lane & 15;
    const int arow = tid >> 2, akoff = (tid & 3) * 8;
    f32x4 acc[2][4];
#pragma unroll
    for (int im = 0; im < 2; ++im)
#pragma unroll
        for (int in = 0; in < 4; ++in)
            acc[im][in] = (f32x4){0.f, 0.f, 0.f, 0.f};

    for (int k0 = 0; k0 < 384; k0 += 32) {
#pragma unroll
        for (int s = 0; s < 3; ++s) {
            short8 a = *(const short8*)(Wp3 + ((size_t)(s * 384 + mb * 64 + arow)) * 384 + k0 + akoff);
            *(short8*)&As[s][arow][akoff] = a;
        }
#pragma unroll
        for (int i = 0; i < 2; ++i) {
            int f = i * 256 + tid;
            int row = f >> 2, koff = (f & 3) * 8;
            short8 bv = *(const short8*)(obt + ((size_t)(nb * 128 + row)) * 384 + k0 + koff);
            *(short8*)&Bs[row][koff] = bv;
        }
        __syncthreads();
        short8 bf[4], af[3][2];
#pragma unroll
        for (int in = 0; in < 4; ++in)
            bf[in] = *(const short8*)&Bs[wn * 64 + in * 16 + lr][quad * 8];
#pragma unroll
        for (int s = 0; s < 3; ++s)
#pragma unroll
            for (int im = 0; im < 2; ++im)
                af[s][im] = *(const short8*)&As[s][wm * 32 + im * 16 + lr][quad * 8];
#pragma unroll
        for (int s = 0; s < 3; ++s)
#pragma unroll
            for (int im = 0; im < 2; ++im)
#pragma unroll
                for (int in = 0; in < 4; ++in)
                    acc[im][in] = __builtin_amdgcn_mfma_f32_16x16x32_bf16(af[s][im], bf[in], acc[im][in], 0, 0, 0);
        __syncthreads();
    }
    const float rs = 1.0f / sqrtf(1.0f + EPS_);
#pragma unroll
    for (int im = 0; im < 2; ++im) {
#pragma unroll
        for (int in = 0; in < 4; ++in) {
            int n_g = nb * 128 + wn * 64 + in * 16 + lr;
            int tb = n_g >> 10, hw = n_g & 1023;
#pragma unroll
            for (int r = 0; r < 4; ++r) {
                int o = mb * 64 + wm * 32 + im * 16 + quad * 4 + r;
                size_t idx = ((size_t)tb * C_ + o) * HW + hw;
                out[idx] = acc[im][in][r] * (g2[o] * rs) + b2[o] + x[idx];
            }
        }
    }
}

extern "C" void kernel_launch(void* const* d_in, const int* in_sizes, int n_in,
                              void* d_out, int out_size, void* d_ws, size_t ws_size,
                              hipStream_t stream) {
    const float* x      = (const float*)d_in[0];
    const float* Wconv  = (const float*)d_in[1];
    const float* gamma1 = (const float*)d_in[2];
    const float* beta1  = (const float*)d_in[3];
    const float* Wproj  = (const float*)d_in[4];
    const float* gamma2 = (const float*)d_in[5];
    const float* beta2  = (const float*)d_in[6];
    const float* frx    = (const float*)d_in[7];
    const float* fra    = (const float*)d_in[8];
    float* out = (float*)d_out;

    unsigned short* ws16 = (unsigned short*)d_ws;
    unsigned short* Bc  = ws16;                 // 6,291,456 u16 (aliased by obt after k_mconv)
    unsigned short* obt = ws16;
    unsigned short* Wc3 = ws16 + 6291456;       // 3,538,944
    unsigned short* Wp3 = ws16 + 9830400;       // 442,368
    unsigned short* xsb = ws16 + 10272768;      // 6,291,456
    unsigned short* y1s = ws16 + 16564224;      // 4,718,592
    unsigned short* y2s = ws16 + 21282816;      // 4,718,592
    unsigned long long* abits = (unsigned long long*)(ws16 + 26001408);  // 786,432 u64 = 6.3 MB

    k_wsplit<<<5184, 256, 0, stream>>>(Wconv, Wproj, Wc3, Wp3);
    k_lif_im2col<<<1536, 256, 0, stream>>>(x, Bc, xsb);
    k_mconv<<<dim3(32, 24), 128, 0, stream>>>(Bc, Wc3, gamma1, beta1, frx, fra, y1s, y2s);
    k_attn_qk<<<dim3(16, 12, 4), 256, 0, stream>>>(xsb, y1s, (unsigned short*)abits);
    k_attn_pv<<<dim3(8, 12, 4), 256, 0, stream>>>(abits, y2s, obt);
    k_mproj<<<dim3(128, 6), 256, 0, stream>>>(obt, Wp3, gamma2, beta2, x, out);
}

// Round 5
// 237.305 us; speedup vs baseline: 1.1368x; 1.1368x over previous
//
#include <hip/hip_runtime.h>
#include <hip/hip_bf16.h>
#include <math.h>

// R12 = R11 verbatim resubmit (container infra flake, same as R1->R2).
// R11: (a) k_mconv reverted verbatim to R9 (proven 45.4 us, 0 conflicts);
//      R10's wave-autonomous depth-1 pipeline regressed to 72 us (all pipes
//      emptier -> per-wave latency exposure; barriers in R9 also ALIGN load
//      issue, doubling in-flight MLP per consumer).
//      (b) k_attn_pv rebalanced: 384 blocks (1.5/CU) of 4 waves ->
//      768 blocks (3/CU) of 2 waves by moving the mg split into the grid.
//      Identical per-wave work/loads/LIF ownership/output addresses.
//      Same transformation that took mconv 53.7 -> 45.4.

typedef __attribute__((ext_vector_type(8))) short short8;
typedef __attribute__((ext_vector_type(4))) float f32x4;

#define T_ 4
#define B_ 4
#define C_ 384
#define HW 1024
#define NH_ 12
#define Np_ 256
#define EPS_ 1e-5f
#define LDK 56

static __device__ __forceinline__ unsigned short f2bf(float f) {
    __hip_bfloat16 h = __float2bfloat16(f);
    return *reinterpret_cast<unsigned short*>(&h);
}
static __device__ __forceinline__ float bf2f(unsigned short u) {
    __hip_bfloat16 h = *reinterpret_cast<__hip_bfloat16*>(&u);
    return __bfloat162float(h);
}
static __device__ __forceinline__ void split3(float w, unsigned short& u0,
                                              unsigned short& u1, unsigned short& u2) {
    u0 = f2bf(w);  float f0 = bf2f(u0);
    float r1 = w - f0;
    u1 = f2bf(r1); float f1 = bf2f(u1);
    u2 = f2bf(r1 - f1);
}

// ---------------- K0: weight 3-way bf16 split ----------------
__global__ __launch_bounds__(256) void k_wsplit(const float* __restrict__ Wc,
                                                const float* __restrict__ Wp,
                                                unsigned short* __restrict__ Wc3,
                                                unsigned short* __restrict__ Wp3) {
    const int NC = 768 * 1536;
    const int NP = 384 * 384;
    int i = blockIdx.x * 256 + threadIdx.x;
    float w; unsigned short* dst; int idx, plane;
    if (i < NC) { w = Wc[i]; dst = Wc3; idx = i; plane = NC; }
    else {
        int j = i - NC;
        if (j >= NP) return;
        w = Wp[j]; dst = Wp3; idx = j; plane = NP;
    }
    unsigned short u0, u1, u2;
    split3(w, u0, u1, u2);
    dst[idx] = u0; dst[plane + idx] = u1; dst[2 * plane + idx] = u2;
}

// ---------------- K1: LIF(x) fused with im2col -> Bc[n][k] bf16, + xsb[tb][c][hw] bf16 ----
__global__ __launch_bounds__(256) void k_lif_im2col(const float* __restrict__ x,
                                                    unsigned short* __restrict__ Bc,
                                                    unsigned short* __restrict__ xsb) {
    int gt = blockIdx.x * 256 + threadIdx.x;
    int pw = gt & 15, ph = (gt >> 4) & 15;
    int v = gt >> 8;
    int c = v % 384, b = v / 384;
    float v00 = 0.f, v01 = 0.f, v10 = 0.f, v11 = 0.f;
    const size_t xrow = ((size_t)b * C_ + c) * HW + (size_t)(2 * ph) * 32 + 2 * pw;
#pragma unroll
    for (int t = 0; t < T_; ++t) {
        const float* px = x + (size_t)t * (B_ * C_ * HW) + xrow;
        float2 r0 = *(const float2*)px;
        float2 r1 = *(const float2*)(px + 32);
        v00 += (r0.x - v00) * 0.5f;
        v01 += (r0.y - v01) * 0.5f;
        v10 += (r1.x - v10) * 0.5f;
        v11 += (r1.y - v11) * 0.5f;
        ushort4 s;
        s.x = (v00 >= 1.f) ? 0x3F80 : 0; if (v00 >= 1.f) v00 = 0.f;
        s.y = (v01 >= 1.f) ? 0x3F80 : 0; if (v01 >= 1.f) v01 = 0.f;
        s.z = (v10 >= 1.f) ? 0x3F80 : 0; if (v10 >= 1.f) v10 = 0.f;
        s.w = (v11 >= 1.f) ? 0x3F80 : 0; if (v11 >= 1.f) v11 = 0.f;
        int tb = t * B_ + b;
        int n = tb * 256 + ph * 16 + pw;
        *(ushort4*)(Bc + (size_t)n * 1536 + 4 * c) = s;
        size_t xo = ((size_t)tb * C_ + c) * HW + (size_t)(2 * ph) * 32 + 2 * pw;
        ushort2 w0 = {s.x, s.y}, w1 = {s.z, s.w};
        *(ushort2*)(xsb + xo) = w0;
        *(ushort2*)(xsb + xo + 32) = w1;
    }
}

// ---------------- K2: conv GEMM via MFMA; epilogue emits scaled 3-split y1s/y2s ----------
// async global->LDS staging, 16B units, within-64B-line XOR swizzle
#define GL16(GP, LP) __builtin_amdgcn_global_load_lds(                        \
    (const __attribute__((address_space(1))) void*)(GP),                      \
    (__attribute__((address_space(3))) void*)(LP), 16, 0, 0)

// LDS layout per buffer (shorts): A[3][32][32] at 0..3071, B[128][32] at 3072..7167.
// LDS[row][c] holds global chunk (c ^ ((row>>1)&3)); swizzle is a permutation
// WITHIN each 64B row -> global coalescing intact, ds_read conflict-minimal.
static __device__ __forceinline__ void stage_conv(const unsigned short* __restrict__ Wc3,
                                                  const unsigned short* __restrict__ Bc,
                                                  short* smb, int mb, int nb, int k0,
                                                  int wid, int rloc, int cswz) {
    if (wid == 0) {
#pragma unroll
        for (int s = 0; s < 3; ++s)
#pragma unroll
            for (int u = 0; u < 2; ++u)
                GL16(Wc3 + ((size_t)(s * 768 + mb * 32 + u * 16 + rloc)) * 1536 + k0 + cswz * 8,
                     smb + s * 1024 + u * 512);
        GL16(Bc + ((size_t)(nb * 128 + rloc)) * 1536 + k0 + cswz * 8, smb + 3072);
    } else {
#pragma unroll
        for (int v = 1; v < 8; ++v)
            GL16(Bc + ((size_t)(nb * 128 + v * 16 + rloc)) * 1536 + k0 + cswz * 8,
                 smb + 3072 + v * 512);
    }
    // exactly 7 global_load_lds per wave per call -> s_waitcnt vmcnt(7) keeps
    // the next tile's loads in flight while completing this tile's.
}

__global__ __launch_bounds__(128) void k_mconv(const unsigned short* __restrict__ Bc,
                                               const unsigned short* __restrict__ Wc3,
                                               const float* __restrict__ g1,
                                               const float* __restrict__ b1,
                                               const float* __restrict__ frx,
                                               const float* __restrict__ fra,
                                               unsigned short* __restrict__ y1s,
                                               unsigned short* __restrict__ y2s) {
    __shared__ short sm[2][7168];                 // 2 x 14,336 B = 28,672 B
    const int nb = blockIdx.x, mb = blockIdx.y;   // nb: 0..31 (N/128), mb: 0..23 (M/32)
    const int tid = threadIdx.x;
    const int lane = tid & 63, wid = tid >> 6;    // 2 waves; wave = N-half owner
    const int quad = lane >> 4, lr = lane & 15;
    const int rloc = lane >> 2;                   // staging: 4 lanes per 64B row
    const int cswz = (lane & 3) ^ ((lane >> 3) & 3);   // source chunk swizzle
    const int slot = quad ^ ((lr >> 1) & 3);      // ds_read chunk swizzle
    const int wn = wid;

    f32x4 acc[2][4];
#pragma unroll
    for (int im = 0; im < 2; ++im)
#pragma unroll
        for (int in = 0; in < 4; ++in)
            acc[im][in] = (f32x4){0.f, 0.f, 0.f, 0.f};

    stage_conv(Wc3, Bc, sm[0], mb, nb, 0, wid, rloc, cswz);   // prologue: K-chunk 0

#pragma unroll 2
    for (int kt = 0; kt < 48; ++kt) {
        const int b = kt & 1;
        if (kt < 47) {
            stage_conv(Wc3, Bc, sm[b ^ 1], mb, nb, (kt + 1) * 32, wid, rloc, cswz);
            asm volatile("s_waitcnt vmcnt(7)" ::: "memory");   // cur done, next in flight
        } else {
            asm volatile("s_waitcnt vmcnt(0)" ::: "memory");
        }
        __builtin_amdgcn_s_barrier();             // cur buffer visible to both waves
        __builtin_amdgcn_sched_barrier(0);        // pin: nothing crosses upward

        const short* smb = sm[b];
        short8 af[3][2], bf[4];
#pragma unroll
        for (int s = 0; s < 3; ++s)
#pragma unroll
            for (int im = 0; im < 2; ++im)
                af[s][im] = *(const short8*)&smb[s * 1024 + (im * 16 + lr) * 32 + slot * 8];
#pragma unroll
        for (int in = 0; in < 4; ++in)
            bf[in] = *(const short8*)&smb[3072 + (wn * 64 + in * 16 + lr) * 32 + slot * 8];
        asm volatile("s_waitcnt lgkmcnt(0)" ::: "memory");  // reads done before WAR barrier
        __builtin_amdgcn_sched_barrier(0);        // pin: no ds_read sinks below wait
        __builtin_amdgcn_s_barrier();             // all waves done reading buf b
        __builtin_amdgcn_sched_barrier(0);        // pin: no stage hoists above barrier

#pragma unroll
        for (int s = 0; s < 3; ++s)
#pragma unroll
            for (int im = 0; im < 2; ++im)
#pragma unroll
                for (int in = 0; in < 4; ++in)
                    acc[im][in] = __builtin_amdgcn_mfma_f32_16x16x32_bf16(af[s][im], bf[in], acc[im][in], 0, 0, 0);
    }

    const float rs = 1.0f / sqrtf(1.0f + EPS_);
    const int h = mb >> 1, half = mb & 1;         // mb*32 = h*64 + half*32
    const float scl = (half == 0) ? (1.0f / sqrtf(frx[h] * 32.0f))
                                  : (1.0f / sqrtf(fra[h] * 256.0f));
    unsigned short* dst = (half == 0) ? y1s : y2s;
#pragma unroll
    for (int im = 0; im < 2; ++im) {
#pragma unroll
        for (int in = 0; in < 4; ++in) {
            int n_g = nb * 128 + wn * 64 + in * 16 + lr;
            int tb = n_g >> 8, pn = n_g & 255;
            size_t base = (size_t)(tb * NH_ + h) * 3 * 8192;
            ushort4 o0, o1, o2;
#pragma unroll
            for (int r = 0; r < 4; ++r) {
                int oc = mb * 32 + im * 16 + quad * 4 + r;
                float val = (acc[im][in][r] * (g1[oc] * rs) + b1[oc]) * scl;
                unsigned short u0, u1, u2;
                split3(val, u0, u1, u2);
                ((unsigned short*)&o0)[r] = u0;
                ((unsigned short*)&o1)[r] = u1;
                ((unsigned short*)&o2)[r] = u2;
            }
            int dd = im * 16 + quad * 4;
            if (half == 0) {
                *(ushort4*)&dst[base + 0 * 8192 + (size_t)pn * 32 + dd] = o0;
                *(ushort4*)&dst[base + 1 * 8192 + (size_t)pn * 32 + dd] = o1;
                *(ushort4*)&dst[base + 2 * 8192 + (size_t)pn * 32 + dd] = o2;
            } else {
#pragma unroll
                for (int r = 0; r < 4; ++r) {
                    dst[base + 0 * 8192 + (size_t)(dd + r) * 256 + pn] = ((unsigned short*)&o0)[r];
                    dst[base + 1 * 8192 + (size_t)(dd + r) * 256 + pn] = ((unsigned short*)&o1)[r];
                    dst[base + 2 * 8192 + (size_t)(dd + r) * 256 + pn] = ((unsigned short*)&o2)[r];
                }
            }
        }
    }
}

// ---------------- K3a: ein1 + attn-LIF -> packed spike bits ----------------
__global__ __launch_bounds__(256, 2) void k_attn_qk(const unsigned short* __restrict__ xsb,
                                                    const unsigned short* __restrict__ y1s,
                                                    unsigned short* __restrict__ abq) {
    __shared__ unsigned short xb[4][64][40];   // [t][m][d] : 20,480 B
    const int h = blockIdx.y, b = blockIdx.z;
    const int tid = threadIdx.x;
    const int lane = tid & 63, wq = tid >> 6;
    const int quad = lane >> 4, lr = lane & 15;
    const int m0 = blockIdx.x * 64;

#pragma unroll
    for (int i = 0; i < 8; ++i) {
        int e = tid + i * 256;                 // 2048 ushort4 = 4t*64m*32d
        int j4 = e & 15, d = (e >> 4) & 31, t = e >> 9;
        ushort4 v = *(const ushort4*)(xsb + ((size_t)((t * B_ + b) * C_) + h * 32 + d) * HW + m0 + j4 * 4);
        xb[t][j4 * 4 + 0][d] = v.x;
        xb[t][j4 * 4 + 1][d] = v.y;
        xb[t][j4 * 4 + 2][d] = v.z;
        xb[t][j4 * 4 + 3][d] = v.w;
    }
    __syncthreads();   // only barrier; t/m loops below are wave-autonomous

    float vat[4][4][4];   // [mi][itl][r] attn-LIF state
#pragma unroll
    for (int mi = 0; mi < 4; ++mi)
#pragma unroll
        for (int itl = 0; itl < 4; ++itl)
#pragma unroll
            for (int r = 0; r < 4; ++r) vat[mi][itl][r] = 0.f;

#pragma unroll
    for (int t = 0; t < T_; ++t) {
        const int tb = t * B_ + b;
        const size_t slab = (size_t)(tb * NH_ + h) * 3 * 8192;

        // m-invariant A-fragments: 12 loads, reused by all 4 m-tiles
        short8 af[3][4];
        const unsigned short* y1p = y1s + slab + (size_t)(wq * 64 + lr) * 32 + quad * 8;
#pragma unroll
        for (int s = 0; s < 3; ++s)
#pragma unroll
            for (int itl = 0; itl < 4; ++itl)
                af[s][itl] = *(const short8*)(y1p + s * 8192 + itl * 512);

#pragma unroll
        for (int mi = 0; mi < 4; ++mi) {
            short8 bx = *(const short8*)&xb[t][mi * 16 + lr][quad * 8];
            f32x4 acc[4];
#pragma unroll
            for (int itl = 0; itl < 4; ++itl) acc[itl] = (f32x4){0.f, 0.f, 0.f, 0.f};
#pragma unroll
            for (int s = 0; s < 3; ++s)
#pragma unroll
                for (int itl = 0; itl < 4; ++itl)
                    acc[itl] = __builtin_amdgcn_mfma_f32_16x16x32_bf16(af[s][itl], bx, acc[itl], 0, 0, 0);

            unsigned int q = 0;
#pragma unroll
            for (int itl = 0; itl < 4; ++itl)
#pragma unroll
                for (int r = 0; r < 4; ++r) {
                    float v = vat[mi][itl][r];
                    v += (acc[itl][r] - v) * 0.5f;
                    bool s = (v >= 1.0f);
                    vat[mi][itl][r] = s ? 0.f : v;
                    q |= (s ? 1u : 0u) << (itl * 4 + r);
                }
            int m = m0 + mi * 16 + lr;
            abq[(((size_t)(tb * NH_ + h) * 1024 + m) * 4 + quad) * 4 + wq] = (unsigned short)q;
        }
    }
}

// ---------------- K3b: ein2 + out-LIF (no LDS, no barriers) ----------------
// R11: rebalanced. Block = 128 thr (2 waves, dt = wave id) covering 64 m-cols;
// grid (16,12,4) = 768 blocks = 3/CU (was 384 = 1.5/CU). Per-wave work, loads,
// LIF-state ownership, and output addresses identical to R7/R9 -> bit-exact.
__global__ __launch_bounds__(128) void k_attn_pv(const unsigned long long* __restrict__ abits,
                                                 const unsigned short* __restrict__ y2s,
                                                 unsigned short* __restrict__ obt) {
    const int h = blockIdx.y, b = blockIdx.z;
    const int tid = threadIdx.x;
    const int lane = tid & 63;
    const int quad = lane >> 4, lr = lane & 15;
    const int dt = tid >> 6;                     // wave id = d-half owner
    const int mbase = blockIdx.x * 64;
    const int obase = (quad & 2) << 1;   // 0 or 4

    float vo[4][4];
#pragma unroll
    for (int mi = 0; mi < 4; ++mi)
#pragma unroll
        for (int r = 0; r < 4; ++r) vo[mi][r] = 0.f;

#pragma unroll
    for (int t = 0; t < T_; ++t) {
        const int tb = t * B_ + b;
        const size_t slab = (size_t)(tb * NH_ + h) * 3 * 8192;

        // m-invariant A-fragments: 24 loads, reused by all 4 m-tiles
        short8 ay[3][8];
        const unsigned short* y2p = y2s + slab + (size_t)(dt * 16 + lr) * 256 + quad * 8;
#pragma unroll
        for (int s = 0; s < 3; ++s)
#pragma unroll
            for (int kt = 0; kt < 8; ++kt)
                ay[s][kt] = *(const short8*)(y2p + s * 8192 + kt * 32);

#pragma unroll
        for (int mi = 0; mi < 4; ++mi) {
            const int m = mbase + mi * 16 + lr;
            const unsigned long long* ap = abits + ((size_t)(tb * NH_ + h) * 1024 + m) * 4 + (quad & 1) * 2;
            unsigned long long Qa = ap[0];
            unsigned long long Qb = ap[1];

            short8 bs[8];
#pragma unroll
            for (int kt = 0; kt < 8; ++kt) {
                int o = kt * 8 + obase;
                unsigned int a4 = (unsigned int)(Qa >> o) & 15u;
                unsigned int b4 = (unsigned int)(Qb >> o) & 15u;
                union { short8 v; unsigned int w[4]; } u;
                u.w[0] = ((a4 & 1u) ? 0x3F80u : 0u) | ((a4 & 2u) ? 0x3F800000u : 0u);
                u.w[1] = ((a4 & 4u) ? 0x3F80u : 0u) | ((a4 & 8u) ? 0x3F800000u : 0u);
                u.w[2] = ((b4 & 1u) ? 0x3F80u : 0u) | ((b4 & 2u) ? 0x3F800000u : 0u);
                u.w[3] = ((b4 & 4u) ? 0x3F80u : 0u) | ((b4 & 8u) ? 0x3F800000u : 0u);
                bs[kt] = u.v;
            }

            f32x4 acc2 = (f32x4){0.f, 0.f, 0.f, 0.f};
#pragma unroll
            for (int s = 0; s < 3; ++s)
#pragma unroll
                for (int kt = 0; kt < 8; ++kt)
                    acc2 = __builtin_amdgcn_mfma_f32_16x16x32_bf16(ay[s][kt], bs[kt], acc2, 0, 0, 0);

            ushort4 ob;
#pragma unroll
            for (int r = 0; r < 4; ++r) {
                float v = vo[mi][r];
                v += (acc2[r] - v) * 0.5f;
                bool s = (v >= 1.0f);
                ((unsigned short*)&ob)[r] = s ? 0x3F80 : 0;
                vo[mi][r] = s ? 0.f : v;
            }
            *(ushort4*)(obt + ((size_t)tb * HW + m) * C_ + h * 32 + dt * 16 + quad * 4) = ob;
        }
    }
}

// ---------------- K4: proj GEMM via MFMA + BN2 + residual ----------------
__global__ __launch_bounds__(256) void k_mproj(const unsigned short* __restrict__ obt,
                                               const unsigned short* __restrict__ Wp3,
                                               const float* __restrict__ g2,
                                               const float* __restrict__ b2,
                                               const float* __restrict__ x,
                                               float* __restrict__ out) {
    __shared__ short As[3][64][LDK];
    __shared__ short Bs[128][LDK];
    const int nb = blockIdx.x, mb = blockIdx.y;
    const int tid = threadIdx.x;
    const int lane = tid & 63, wave = tid >> 6;
    const int wm = wave >> 1, wn = wave & 1;
    const int quad = lane >> 4, lr = lane & 15;
    const int arow = tid >> 2, akoff = (tid & 3) * 8;
    f32x4 acc[2][4];
#pragma unroll
    for (int im = 0; im < 2; ++im)
#pragma unroll
        for (int in = 0; in < 4; ++in)
            acc[im][in] = (f32x4){0.f, 0.f, 0.f, 0.f};

    for (int k0 = 0; k0 < 384; k0 += 32) {
#pragma unroll
        for (int s = 0; s < 3; ++s) {
            short8 a = *(const short8*)(Wp3 + ((size_t)(s * 384 + mb * 64 + arow)) * 384 + k0 + akoff);
            *(short8*)&As[s][arow][akoff] = a;
        }
#pragma unroll
        for (int i = 0; i < 2; ++i) {
            int f = i * 256 + tid;
            int row = f >> 2, koff = (f & 3) * 8;
            short8 bv = *(const short8*)(obt + ((size_t)(nb * 128 + row)) * 384 + k0 + koff);
            *(short8*)&Bs[row][koff] = bv;
        }
        __syncthreads();
        short8 bf[4], af[3][2];
#pragma unroll
        for (int in = 0; in < 4; ++in)
            bf[in] = *(const short8*)&Bs[wn * 64 + in * 16 + lr][quad * 8];
#pragma unroll
        for (int s = 0; s < 3; ++s)
#pragma unroll
            for (int im = 0; im < 2; ++im)
                af[s][im] = *(const short8*)&As[s][wm * 32 + im * 16 + lr][quad * 8];
#pragma unroll
        for (int s = 0; s < 3; ++s)
#pragma unroll
            for (int im = 0; im < 2; ++im)
#pragma unroll
                for (int in = 0; in < 4; ++in)
                    acc[im][in] = __builtin_amdgcn_mfma_f32_16x16x32_bf16(af[s][im], bf[in], acc[im][in], 0, 0, 0);
        __syncthreads();
    }
    const float rs = 1.0f / sqrtf(1.0f + EPS_);
#pragma unroll
    for (int im = 0; im < 2; ++im) {
#pragma unroll
        for (int in = 0; in < 4; ++in) {
            int n_g = nb * 128 + wn * 64 + in * 16 + lr;
            int tb = n_g >> 10, hw = n_g & 1023;
#pragma unroll
            for (int r = 0; r < 4; ++r) {
                int o = mb * 64 + wm * 32 + im * 16 + quad * 4 + r;
                size_t idx = ((size_t)tb * C_ + o) * HW + hw;
                out[idx] = acc[im][in][r] * (g2[o] * rs) + b2[o] + x[idx];
            }
        }
    }
}

extern "C" void kernel_launch(void* const* d_in, const int* in_sizes, int n_in,
                              void* d_out, int out_size, void* d_ws, size_t ws_size,
                              hipStream_t stream) {
    const float* x      = (const float*)d_in[0];
    const float* Wconv  = (const float*)d_in[1];
    const float* gamma1 = (const float*)d_in[2];
    const float* beta1  = (const float*)d_in[3];
    const float* Wproj  = (const float*)d_in[4];
    const float* gamma2 = (const float*)d_in[5];
    const float* beta2  = (const float*)d_in[6];
    const float* frx    = (const float*)d_in[7];
    const float* fra    = (const float*)d_in[8];
    float* out = (float*)d_out;

    unsigned short* ws16 = (unsigned short*)d_ws;
    unsigned short* Bc  = ws16;                 // 6,291,456 u16 (aliased by obt after k_mconv)
    unsigned short* obt = ws16;
    unsigned short* Wc3 = ws16 + 6291456;       // 3,538,944
    unsigned short* Wp3 = ws16 + 9830400;       // 442,368
    unsigned short* xsb = ws16 + 10272768;      // 6,291,456
    unsigned short* y1s = ws16 + 16564224;      // 4,718,592
    unsigned short* y2s = ws16 + 21282816;      // 4,718,592
    unsigned long long* abits = (unsigned long long*)(ws16 + 26001408);  // 786,432 u64 = 6.3 MB

    k_wsplit<<<5184, 256, 0, stream>>>(Wconv, Wproj, Wc3, Wp3);
    k_lif_im2col<<<1536, 256, 0, stream>>>(x, Bc, xsb);
    k_mconv<<<dim3(32, 24), 128, 0, stream>>>(Bc, Wc3, gamma1, beta1, frx, fra, y1s, y2s);
    k_attn_qk<<<dim3(16, 12, 4), 256, 0, stream>>>(xsb, y1s, (unsigned short*)abits);
    k_attn_pv<<<dim3(16, 12, 4), 128, 0, stream>>>(abits, y2s, obt);
    k_mproj<<<dim3(128, 6), 256, 0, stream>>>(obt, Wp3, gamma2, beta2, x, out);
}